// Round 1
// baseline (482.562 us; speedup 1.0000x reference)
//
#include <hip/hip_runtime.h>
#include <hip/hip_bf16.h>
#include <stdint.h>

typedef __attribute__((ext_vector_type(8))) short bf16x8;
typedef __attribute__((ext_vector_type(4))) float f32x4;

#define LSEQ 2048
#define DM 1024
#define NH 16
#define HD 64

__device__ __forceinline__ unsigned short bf16r(float f) {
  unsigned u = __builtin_bit_cast(unsigned, f);
  u = (u + 0x7FFFu + ((u >> 16) & 1u)) >> 16;
  return (unsigned short)u;
}
__device__ __forceinline__ float bf16f(unsigned short h) {
  unsigned u = ((unsigned)h) << 16;
  return __builtin_bit_cast(float, u);
}

__device__ __forceinline__ void async16(const void* g, void* l) {
  __builtin_amdgcn_global_load_lds(
      (const __attribute__((address_space(1))) unsigned int*)g,
      (__attribute__((address_space(3))) unsigned int*)l, 16, 0, 0);
}

// swizzled ds_read_b128 from a row-major LDS tile (T2 XOR swizzle, byte ^= (row&7)<<4)
template <int ROWB>
__device__ __forceinline__ bf16x8 lds_frag_swz(const unsigned short* base, int row, int colbyte) {
  int addr = row * ROWB + colbyte;
  addr ^= ((row & 7) << 4);
  return *(const bf16x8*)((const char*)base + addr);
}

// ---------------- f32 -> bf16 convert ----------------
__global__ __launch_bounds__(256) void cvt_bf16(const float* __restrict__ s,
                                                unsigned short* __restrict__ d, int n8) {
  int i = blockIdx.x * 256 + threadIdx.x;
  if (i >= n8) return;
  const float4* sp = (const float4*)s;
  float4 a = sp[2 * i], b = sp[2 * i + 1];
  union { unsigned short u[8]; uint4 v; } r;
  r.u[0] = bf16r(a.x); r.u[1] = bf16r(a.y); r.u[2] = bf16r(a.z); r.u[3] = bf16r(a.w);
  r.u[4] = bf16r(b.x); r.u[5] = bf16r(b.y); r.u[6] = bf16r(b.z); r.u[7] = bf16r(b.w);
  ((uint4*)d)[i] = r.v;
}

// ---------------- GEMM: C[M=4096,N=1024] = A[M,1024] @ Bw[N,1024]^T + bias ----------------
// MODE 0: bf16 out; MODE 1: bf16 out with per-64-col L2 normalization (post-bias); MODE 2: f32 out
template <int MODE>
__global__ __launch_bounds__(256) void gemm_bt(const unsigned short* __restrict__ A,
                                               const unsigned short* __restrict__ Bw,
                                               const float* __restrict__ bias,
                                               void* __restrict__ Cout) {
  __shared__ unsigned short As[128 * 64];
  __shared__ unsigned short Bs[128 * 64];
  const int t = threadIdx.x, lane = t & 63, wid = t >> 6;
  const int mt = blockIdx.x, nt = blockIdx.y;
  const int wm = (wid >> 1) * 64, wn = (wid & 1) * 64;
  const int lq = lane >> 4, lr = lane & 15;

  f32x4 acc[4][4];
#pragma unroll
  for (int i = 0; i < 4; ++i)
#pragma unroll
    for (int j = 0; j < 4; ++j) acc[i][j] = (f32x4){0.f, 0.f, 0.f, 0.f};

  auto stage = [&](int k0) {
#pragma unroll
    for (int i = 0; i < 4; ++i) {
      int chunk = i * 256 + t;
      int row = chunk >> 3, j = chunk & 7;
      int sj = j ^ (row & 7);  // pre-swizzled global source -> linear LDS dest
      async16(A + (size_t)(mt * 128 + row) * DM + k0 + sj * 8, (char*)As + chunk * 16);
    }
#pragma unroll
    for (int i = 0; i < 4; ++i) {
      int chunk = i * 256 + t;
      int row = chunk >> 3, j = chunk & 7;
      int sj = j ^ (row & 7);
      async16(Bw + (size_t)(nt * 128 + row) * DM + k0 + sj * 8, (char*)Bs + chunk * 16);
    }
  };

  stage(0);
  for (int kt = 0; kt < DM / 64; ++kt) {
    __syncthreads();  // staging of kt visible (vmcnt drained before barrier)
    bf16x8 af[4][2], bfr[4][2];
#pragma unroll
    for (int mf = 0; mf < 4; ++mf) {
      int row = wm + mf * 16 + lr;
#pragma unroll
      for (int ks = 0; ks < 2; ++ks)
        af[mf][ks] = lds_frag_swz<128>(As, row, ks * 64 + lq * 16);
    }
#pragma unroll
    for (int nf = 0; nf < 4; ++nf) {
      int row = wn + nf * 16 + lr;
#pragma unroll
      for (int ks = 0; ks < 2; ++ks)
        bfr[nf][ks] = lds_frag_swz<128>(Bs, row, ks * 64 + lq * 16);
    }
    __syncthreads();  // all LDS reads done
    if (kt + 1 < DM / 64) stage((kt + 1) * 64);  // overlap staging with MFMA
#pragma unroll
    for (int ks = 0; ks < 2; ++ks)
#pragma unroll
      for (int mf = 0; mf < 4; ++mf)
#pragma unroll
        for (int nf = 0; nf < 4; ++nf)
          acc[mf][nf] = __builtin_amdgcn_mfma_f32_16x16x32_bf16(af[mf][ks], bfr[nf][ks],
                                                                acc[mf][nf], 0, 0, 0);
  }

  const int gn0 = nt * 128 + wn;
  float bv[4];
#pragma unroll
  for (int nf = 0; nf < 4; ++nf) bv[nf] = bias[gn0 + nf * 16 + lr];
#pragma unroll
  for (int mf = 0; mf < 4; ++mf) {
    float v[4][4];
#pragma unroll
    for (int nf = 0; nf < 4; ++nf)
#pragma unroll
      for (int r = 0; r < 4; ++r) v[nf][r] = acc[mf][nf][r] + bv[nf];
    if (MODE == 1) {
      // per-row L2 norm over the wave's 64 cols (= one head)
#pragma unroll
      for (int r = 0; r < 4; ++r) {
        float ss = v[0][r] * v[0][r] + v[1][r] * v[1][r] + v[2][r] * v[2][r] + v[3][r] * v[3][r];
        ss += __shfl_xor(ss, 1, 64);
        ss += __shfl_xor(ss, 2, 64);
        ss += __shfl_xor(ss, 4, 64);
        ss += __shfl_xor(ss, 8, 64);
        float rn = 1.0f / fmaxf(sqrtf(ss), 1e-12f);
#pragma unroll
        for (int nf = 0; nf < 4; ++nf) v[nf][r] *= rn;
      }
    }
    const int gm0 = mt * 128 + wm + mf * 16 + lq * 4;
    if (MODE == 2) {
      float* C = (float*)Cout;
#pragma unroll
      for (int r = 0; r < 4; ++r)
#pragma unroll
        for (int nf = 0; nf < 4; ++nf)
          C[(size_t)(gm0 + r) * DM + gn0 + nf * 16 + lr] = v[nf][r];
    } else {
      unsigned short* C = (unsigned short*)Cout;
#pragma unroll
      for (int r = 0; r < 4; ++r)
#pragma unroll
        for (int nf = 0; nf < 4; ++nf)
          C[(size_t)(gm0 + r) * DM + gn0 + nf * 16 + lr] = bf16r(v[nf][r]);
    }
  }
}

// ---------------- V [B,L,1024](bf16) -> Vt [B,H,64,L](bf16) ----------------
__global__ __launch_bounds__(256) void transpose_v(const unsigned short* __restrict__ V,
                                                   unsigned short* __restrict__ Vt) {
  __shared__ unsigned short T[64][72];
  const int lt = blockIdx.x, h = blockIdx.y, b = blockIdx.z;
  const int t = threadIdx.x;
  const int r = t >> 2, c0 = (t & 3) * 16;
  const unsigned short* g = V + ((size_t)(b * LSEQ + lt * 64 + r) * DM + h * 64 + c0);
  *(uint4*)&T[r][c0] = *(const uint4*)g;
  *(uint4*)&T[r][c0 + 8] = *(const uint4*)(g + 8);
  __syncthreads();
  const int d = t >> 2, l0 = (t & 3) * 16;
  union { unsigned short u[16]; uint4 v[2]; } o;
#pragma unroll
  for (int j = 0; j < 16; ++j) o.u[j] = T[l0 + j][d];
  unsigned short* og = Vt + ((size_t)((b * NH + h) * HD + d) * LSEQ + lt * 64 + l0);
  ((uint4*)og)[0] = o.v[0];
  ((uint4*)og)[1] = o.v[1];
}

// ---------------- fused cosine attention ----------------
// grid (L/64, H, B), 256 thr. Wave w owns q-rows [w*16, w*16+16).
__global__ __launch_bounds__(256) void attn_kernel(
    const unsigned short* __restrict__ Qn, const unsigned short* __restrict__ Kn,
    const unsigned short* __restrict__ Vt, const int* __restrict__ mask,
    const float* __restrict__ scale_p, float* __restrict__ attn_out,
    unsigned short* __restrict__ ctx) {
  __shared__ unsigned short Qs[64 * 64];    // [q][d]   swizzled, 128B rows
  __shared__ unsigned short Ks[128 * 64];   // [key][d] swizzled, 128B rows
  __shared__ unsigned short Vs[64 * 128];   // [d][key] swizzled, 256B rows
  __shared__ unsigned short Ps[64 * 136];   // [q][key] padded (+8), unswizzled
  const int qt = blockIdx.x, h = blockIdx.y, b = blockIdx.z;
  const int t = threadIdx.x, lane = t & 63, wid = t >> 6;
  const int lq = lane >> 4, lr = lane & 15;
  const int wq = wid * 16;
  const float scale = scale_p[0];
  const float L2E = 1.4426950408889634f;

  const unsigned short* Qg = Qn + ((size_t)(b * LSEQ + qt * 64) * DM + h * HD);
  const unsigned short* Kg = Kn + ((size_t)b * LSEQ * DM + h * HD);
  const unsigned short* Vg = Vt + (size_t)(b * NH + h) * HD * LSEQ;
  float* attn_g = attn_out + ((size_t)((b * NH + h) * LSEQ + qt * 64)) * LSEQ;
  const int* mg = mask + b * LSEQ;

  auto stageK = [&](int k0) {
#pragma unroll
    for (int i = 0; i < 4; ++i) {
      int chunk = i * 256 + t;
      int row = chunk >> 3, j = chunk & 7;
      async16(Kg + (size_t)(k0 + row) * DM + (j ^ (row & 7)) * 8, (char*)Ks + chunk * 16);
    }
  };
  auto stageV = [&](int k0) {
#pragma unroll
    for (int i = 0; i < 4; ++i) {
      int chunk = i * 256 + t;
      int row = chunk >> 4, j = chunk & 15;
      async16(Vg + (size_t)row * LSEQ + k0 + (j ^ (row & 7)) * 8, (char*)Vs + chunk * 16);
    }
  };

  // stage Q (once) + K tile 0
#pragma unroll
  for (int i = 0; i < 2; ++i) {
    int chunk = i * 256 + t;
    int row = chunk >> 3, j = chunk & 7;
    async16(Qg + (size_t)row * DM + (j ^ (row & 7)) * 8, (char*)Qs + chunk * 16);
  }
  stageK(0);

  bf16x8 qa[2];
  float rmax[4], rsum[4];
#pragma unroll
  for (int r = 0; r < 4; ++r) { rmax[r] = -3e38f; rsum[r] = 0.f; }

  auto qk_tile = [&](f32x4 (&c)[8]) {
#pragma unroll
    for (int nf = 0; nf < 8; ++nf) {
      int row = nf * 16 + lr;
      bf16x8 k0f = lds_frag_swz<128>(Ks, row, lq * 16);
      bf16x8 k1f = lds_frag_swz<128>(Ks, row, 64 + lq * 16);
      f32x4 z = (f32x4){0.f, 0.f, 0.f, 0.f};
      z = __builtin_amdgcn_mfma_f32_16x16x32_bf16(qa[0], k0f, z, 0, 0, 0);
      z = __builtin_amdgcn_mfma_f32_16x16x32_bf16(qa[1], k1f, z, 0, 0, 0);
      c[nf] = z;
    }
  };

  // ---- pass 1: softmax stats (online max/sum) ----
  for (int kt = 0; kt < LSEQ / 128; ++kt) {
    __syncthreads();
    if (kt == 0) {
      int row = wq + lr;
      qa[0] = lds_frag_swz<128>(Qs, row, lq * 16);
      qa[1] = lds_frag_swz<128>(Qs, row, 64 + lq * 16);
    }
    f32x4 c[8];
    qk_tile(c);
    __syncthreads();
    if (kt + 1 < LSEQ / 128) stageK((kt + 1) * 128);
    float s[8][4];
#pragma unroll
    for (int nf = 0; nf < 8; ++nf) {
      int mv = mg[kt * 128 + nf * 16 + lr];
#pragma unroll
      for (int r = 0; r < 4; ++r) s[nf][r] = (mv == 0) ? -1e18f : scale * c[nf][r];
    }
#pragma unroll
    for (int r = 0; r < 4; ++r) {
      float lm = s[0][r];
#pragma unroll
      for (int nf = 1; nf < 8; ++nf) lm = fmaxf(lm, s[nf][r]);
      float nm = fmaxf(rmax[r], lm);
      float a = 0.f;
#pragma unroll
      for (int nf = 0; nf < 8; ++nf) a += exp2f((s[nf][r] - nm) * L2E);
      rsum[r] = rsum[r] * exp2f((rmax[r] - nm) * L2E) + a;
      rmax[r] = nm;
    }
  }
  // merge across the 16 column-lanes
#pragma unroll
  for (int off = 1; off < 16; off <<= 1) {
#pragma unroll
    for (int r = 0; r < 4; ++r) {
      float om = __shfl_xor(rmax[r], off, 64);
      float os = __shfl_xor(rsum[r], off, 64);
      float nm = fmaxf(rmax[r], om);
      rsum[r] = rsum[r] * exp2f((rmax[r] - nm) * L2E) + os * exp2f((om - nm) * L2E);
      rmax[r] = nm;
    }
  }
  float sinv[4];
#pragma unroll
  for (int r = 0; r < 4; ++r) sinv[r] = 1.0f / rsum[r];

  // ---- pass 2: recompute scores, write attn, accumulate PV ----
  f32x4 opv[4];
#pragma unroll
  for (int nf = 0; nf < 4; ++nf) opv[nf] = (f32x4){0.f, 0.f, 0.f, 0.f};
  stageK(0);
  stageV(0);
  for (int kt = 0; kt < LSEQ / 128; ++kt) {
    __syncthreads();  // K,V staged
    f32x4 c[8];
    qk_tile(c);
#pragma unroll
    for (int nf = 0; nf < 8; ++nf) {
      int mv = mg[kt * 128 + nf * 16 + lr];
#pragma unroll
      for (int r = 0; r < 4; ++r) {
        float sc = (mv == 0) ? -1e18f : scale * c[nf][r];
        float p = exp2f((sc - rmax[r]) * L2E) * sinv[r];
        Ps[(wq + lq * 4 + r) * 136 + nf * 16 + lr] = bf16r(p);
      }
    }
    __syncthreads();  // Ps visible; Ks reads done
    if (kt + 1 < LSEQ / 128) stageK((kt + 1) * 128);
    // coalesced attn store from Ps
    {
      int row = t >> 2, cb = (t & 3) * 32;
      float* og = attn_g + (size_t)row * LSEQ + kt * 128 + cb;
#pragma unroll
      for (int gi = 0; gi < 4; ++gi) {
        bf16x8 p8 = *(const bf16x8*)&Ps[row * 136 + cb + gi * 8];
        float4 f0, f1;
        f0.x = bf16f((unsigned short)p8[0]); f0.y = bf16f((unsigned short)p8[1]);
        f0.z = bf16f((unsigned short)p8[2]); f0.w = bf16f((unsigned short)p8[3]);
        f1.x = bf16f((unsigned short)p8[4]); f1.y = bf16f((unsigned short)p8[5]);
        f1.z = bf16f((unsigned short)p8[6]); f1.w = bf16f((unsigned short)p8[7]);
        ((float4*)og)[gi * 2 + 0] = f0;
        ((float4*)og)[gi * 2 + 1] = f1;
      }
    }
    // PV: ctx[q][d] += P[q][k] * Vt[d][k]
#pragma unroll
    for (int ks = 0; ks < 4; ++ks) {
      bf16x8 pa = *(const bf16x8*)((const char*)Ps + (wq + lr) * 272 + ks * 64 + lq * 16);
#pragma unroll
      for (int nf = 0; nf < 4; ++nf) {
        bf16x8 vb = lds_frag_swz<256>(Vs, nf * 16 + lr, ks * 64 + lq * 16);
        opv[nf] = __builtin_amdgcn_mfma_f32_16x16x32_bf16(pa, vb, opv[nf], 0, 0, 0);
      }
    }
    __syncthreads();  // Ps/Vs reads done
    if (kt + 1 < LSEQ / 128) stageV((kt + 1) * 128);
  }
#pragma unroll
  for (int nf = 0; nf < 4; ++nf)
#pragma unroll
    for (int r = 0; r < 4; ++r) {
      int q = wq + lq * 4 + r;
      int d = nf * 16 + lr;
      ctx[(size_t)(b * LSEQ + qt * 64 + q) * DM + h * HD + d] = bf16r(opv[nf][r]);
    }
}

extern "C" void kernel_launch(void* const* d_in, const int* in_sizes, int n_in,
                              void* d_out, int out_size, void* d_ws, size_t ws_size,
                              hipStream_t stream) {
  const float* query = (const float*)d_in[0];
  const float* key_ = (const float*)d_in[1];
  const float* value = (const float*)d_in[2];
  const int* mask = (const int*)d_in[3];
  const float* Wq = (const float*)d_in[4];
  const float* bq = (const float*)d_in[5];
  const float* Wk = (const float*)d_in[6];
  const float* bk = (const float*)d_in[7];
  const float* Wv = (const float*)d_in[8];
  const float* bv = (const float*)d_in[9];
  const float* Wo = (const float*)d_in[10];
  const float* bo = (const float*)d_in[11];
  const float* scale = (const float*)d_in[12];

  char* ws = (char*)d_ws;
  const size_t XB = 8388608;   // 4Mi bf16
  const size_t WB = 2097152;   // 1Mi bf16
  unsigned short* qb = (unsigned short*)(ws);
  unsigned short* kb = (unsigned short*)(ws + XB);
  unsigned short* vb = (unsigned short*)(ws + 2 * XB);
  unsigned short* wqb = (unsigned short*)(ws + 3 * XB);
  unsigned short* wkb = (unsigned short*)(ws + 3 * XB + WB);
  unsigned short* wvb = (unsigned short*)(ws + 3 * XB + 2 * WB);
  unsigned short* wob = (unsigned short*)(ws + 3 * XB + 3 * WB);
  unsigned short* Qnb = (unsigned short*)(ws + 3 * XB + 4 * WB);
  unsigned short* Knb = (unsigned short*)(ws + 4 * XB + 4 * WB);
  unsigned short* Vb = (unsigned short*)(ws + 5 * XB + 4 * WB);
  unsigned short* Vtb = (unsigned short*)(ws + 6 * XB + 4 * WB);
  unsigned short* ctxb = (unsigned short*)(ws + 7 * XB + 4 * WB);

  cvt_bf16<<<2048, 256, 0, stream>>>(query, qb, 524288);
  cvt_bf16<<<2048, 256, 0, stream>>>(key_, kb, 524288);
  cvt_bf16<<<2048, 256, 0, stream>>>(value, vb, 524288);
  cvt_bf16<<<512, 256, 0, stream>>>(Wq, wqb, 131072);
  cvt_bf16<<<512, 256, 0, stream>>>(Wk, wkb, 131072);
  cvt_bf16<<<512, 256, 0, stream>>>(Wv, wvb, 131072);
  cvt_bf16<<<512, 256, 0, stream>>>(Wo, wob, 131072);

  dim3 gg(32, 8, 1);
  gemm_bt<1><<<gg, 256, 0, stream>>>(qb, wqb, bq, Qnb);
  gemm_bt<1><<<gg, 256, 0, stream>>>(kb, wkb, bk, Knb);
  gemm_bt<0><<<gg, 256, 0, stream>>>(vb, wvb, bv, Vb);
  transpose_v<<<dim3(32, NH, 2), 256, 0, stream>>>(Vb, Vtb);

  float* attn_out = (float*)d_out + 4194304;
  attn_kernel<<<dim3(32, NH, 2), 256, 0, stream>>>(Qnb, Knb, Vtb, mask, scale, attn_out, ctxb);

  gemm_bt<2><<<gg, 256, 0, stream>>>(ctxb, wob, bo, d_out);
}

// Round 3
// 291.629 us; speedup vs baseline: 1.6547x; 1.6547x over previous
//
#include <hip/hip_runtime.h>
#include <hip/hip_bf16.h>
#include <stdint.h>

typedef __attribute__((ext_vector_type(8))) short bf16x8;
typedef __attribute__((ext_vector_type(4))) float f32x4;

#define LSEQ 2048
#define DM 1024
#define NH 16
#define HD 64

__device__ __forceinline__ unsigned short bf16r(float f) {
  unsigned u = __builtin_bit_cast(unsigned, f);
  u = (u + 0x7FFFu + ((u >> 16) & 1u)) >> 16;
  return (unsigned short)u;
}
__device__ __forceinline__ float bf16f(unsigned short h) {
  unsigned u = ((unsigned)h) << 16;
  return __builtin_bit_cast(float, u);
}

__device__ __forceinline__ void async16(const void* g, void* l) {
  __builtin_amdgcn_global_load_lds(
      (const __attribute__((address_space(1))) unsigned int*)g,
      (__attribute__((address_space(3))) unsigned int*)l, 16, 0, 0);
}

// swizzled ds_read_b128 from a row-major LDS tile (T2 XOR swizzle, byte ^= (row&7)<<4)
template <int ROWB>
__device__ __forceinline__ bf16x8 lds_frag_swz(const unsigned short* base, int row, int colbyte) {
  int addr = row * ROWB + colbyte;
  addr ^= ((row & 7) << 4);
  return *(const bf16x8*)((const char*)base + addr);
}
// swizzled scalar bf16 store into a 256B-row tile
__device__ __forceinline__ void lds_store16_swz(unsigned short* base, int row, int col,
                                                unsigned short v) {
  int addr = row * 256 + col * 2;
  addr ^= ((row & 7) << 4);
  *(unsigned short*)((char*)base + addr) = v;
}

// ---------------- f32 -> bf16 converts (fused multi-tensor) ----------------
__global__ __launch_bounds__(256) void cvt3(const float* __restrict__ s0,
                                            const float* __restrict__ s1,
                                            const float* __restrict__ s2,
                                            unsigned short* __restrict__ d0,
                                            unsigned short* __restrict__ d1,
                                            unsigned short* __restrict__ d2, int n8) {
  int y = blockIdx.y;
  const float* s = (y == 0) ? s0 : (y == 1) ? s1 : s2;
  unsigned short* d = (y == 0) ? d0 : (y == 1) ? d1 : d2;
  int i = blockIdx.x * 256 + threadIdx.x;
  if (i >= n8) return;
  const float4* sp = (const float4*)s;
  float4 a = sp[2 * i], b = sp[2 * i + 1];
  union { unsigned short u[8]; uint4 v; } r;
  r.u[0] = bf16r(a.x); r.u[1] = bf16r(a.y); r.u[2] = bf16r(a.z); r.u[3] = bf16r(a.w);
  r.u[4] = bf16r(b.x); r.u[5] = bf16r(b.y); r.u[6] = bf16r(b.z); r.u[7] = bf16r(b.w);
  ((uint4*)d)[i] = r.v;
}
__global__ __launch_bounds__(256) void cvt4(const float* __restrict__ s0,
                                            const float* __restrict__ s1,
                                            const float* __restrict__ s2,
                                            const float* __restrict__ s3,
                                            unsigned short* __restrict__ d0,
                                            unsigned short* __restrict__ d1,
                                            unsigned short* __restrict__ d2,
                                            unsigned short* __restrict__ d3, int n8) {
  int y = blockIdx.y;
  const float* s = (y == 0) ? s0 : (y == 1) ? s1 : (y == 2) ? s2 : s3;
  unsigned short* d = (y == 0) ? d0 : (y == 1) ? d1 : (y == 2) ? d2 : d3;
  int i = blockIdx.x * 256 + threadIdx.x;
  if (i >= n8) return;
  const float4* sp = (const float4*)s;
  float4 a = sp[2 * i], b = sp[2 * i + 1];
  union { unsigned short u[8]; uint4 v; } r;
  r.u[0] = bf16r(a.x); r.u[1] = bf16r(a.y); r.u[2] = bf16r(a.z); r.u[3] = bf16r(a.w);
  r.u[4] = bf16r(b.x); r.u[5] = bf16r(b.y); r.u[6] = bf16r(b.z); r.u[7] = bf16r(b.w);
  ((uint4*)d)[i] = r.v;
}

// ---------------- GEMM core: C[4096,1024] = A @ W^T + bias ----------------
// mode 0: bf16 out; mode 1: bf16 out + per-64-col L2 norm; mode 2: f32 out
__device__ __forceinline__ void gemm_core(const unsigned short* __restrict__ A,
                                          const unsigned short* __restrict__ Bw,
                                          const float* __restrict__ bias,
                                          void* __restrict__ Cout, int mode,
                                          unsigned short* As, unsigned short* Bs) {
  const int t = threadIdx.x, lane = t & 63, wid = t >> 6;
  const int mt = blockIdx.x, nt = blockIdx.y;
  const int wm = (wid >> 1) * 64, wn = (wid & 1) * 64;
  const int lq = lane >> 4, lr = lane & 15;

  f32x4 acc[4][4];
#pragma unroll
  for (int i = 0; i < 4; ++i)
#pragma unroll
    for (int j = 0; j < 4; ++j) acc[i][j] = (f32x4){0.f, 0.f, 0.f, 0.f};

  auto stage = [&](int k0) {
#pragma unroll
    for (int i = 0; i < 4; ++i) {
      int chunk = i * 256 + t;
      int row = chunk >> 3, j = chunk & 7;
      int sj = j ^ (row & 7);
      async16(A + (size_t)(mt * 128 + row) * DM + k0 + sj * 8, (char*)As + chunk * 16);
    }
#pragma unroll
    for (int i = 0; i < 4; ++i) {
      int chunk = i * 256 + t;
      int row = chunk >> 3, j = chunk & 7;
      int sj = j ^ (row & 7);
      async16(Bw + (size_t)(nt * 128 + row) * DM + k0 + sj * 8, (char*)Bs + chunk * 16);
    }
  };

  stage(0);
  for (int kt = 0; kt < DM / 64; ++kt) {
    __syncthreads();
    bf16x8 af[4][2], bfr[4][2];
#pragma unroll
    for (int mf = 0; mf < 4; ++mf) {
      int row = wm + mf * 16 + lr;
#pragma unroll
      for (int ks = 0; ks < 2; ++ks)
        af[mf][ks] = lds_frag_swz<128>(As, row, ks * 64 + lq * 16);
    }
#pragma unroll
    for (int nf = 0; nf < 4; ++nf) {
      int row = wn + nf * 16 + lr;
#pragma unroll
      for (int ks = 0; ks < 2; ++ks)
        bfr[nf][ks] = lds_frag_swz<128>(Bs, row, ks * 64 + lq * 16);
    }
    __syncthreads();
    if (kt + 1 < DM / 64) stage((kt + 1) * 64);
#pragma unroll
    for (int ks = 0; ks < 2; ++ks)
#pragma unroll
      for (int mf = 0; mf < 4; ++mf)
#pragma unroll
        for (int nf = 0; nf < 4; ++nf)
          acc[mf][nf] = __builtin_amdgcn_mfma_f32_16x16x32_bf16(af[mf][ks], bfr[nf][ks],
                                                                acc[mf][nf], 0, 0, 0);
  }

  const int gn0 = nt * 128 + wn;
  float bv[4];
#pragma unroll
  for (int nf = 0; nf < 4; ++nf) bv[nf] = bias[gn0 + nf * 16 + lr];
#pragma unroll
  for (int mf = 0; mf < 4; ++mf) {
    float v[4][4];
#pragma unroll
    for (int nf = 0; nf < 4; ++nf)
#pragma unroll
      for (int r = 0; r < 4; ++r) v[nf][r] = acc[mf][nf][r] + bv[nf];
    if (mode == 1) {
#pragma unroll
      for (int r = 0; r < 4; ++r) {
        float ss = v[0][r] * v[0][r] + v[1][r] * v[1][r] + v[2][r] * v[2][r] + v[3][r] * v[3][r];
        ss += __shfl_xor(ss, 1, 64);
        ss += __shfl_xor(ss, 2, 64);
        ss += __shfl_xor(ss, 4, 64);
        ss += __shfl_xor(ss, 8, 64);
        float rn = 1.0f / fmaxf(sqrtf(ss), 1e-12f);
#pragma unroll
        for (int nf = 0; nf < 4; ++nf) v[nf][r] *= rn;
      }
    }
    const int gm0 = mt * 128 + wm + mf * 16 + lq * 4;
    if (mode == 2) {
      float* C = (float*)Cout;
#pragma unroll
      for (int r = 0; r < 4; ++r)
#pragma unroll
        for (int nf = 0; nf < 4; ++nf)
          C[(size_t)(gm0 + r) * DM + gn0 + nf * 16 + lr] = v[nf][r];
    } else {
      unsigned short* C = (unsigned short*)Cout;
#pragma unroll
      for (int r = 0; r < 4; ++r)
#pragma unroll
        for (int nf = 0; nf < 4; ++nf)
          C[(size_t)(gm0 + r) * DM + gn0 + nf * 16 + lr] = bf16r(v[nf][r]);
    }
  }
}

__global__ __launch_bounds__(256) void gemm_qkv(
    const unsigned short* __restrict__ A0, const unsigned short* __restrict__ A1,
    const unsigned short* __restrict__ A2, const unsigned short* __restrict__ W0,
    const unsigned short* __restrict__ W1, const unsigned short* __restrict__ W2,
    const float* __restrict__ b0, const float* __restrict__ b1, const float* __restrict__ b2,
    unsigned short* __restrict__ C0, unsigned short* __restrict__ C1,
    unsigned short* __restrict__ C2) {
  __shared__ unsigned short As[128 * 64];
  __shared__ unsigned short Bs[128 * 64];
  int z = blockIdx.z;
  const unsigned short* A = (z == 0) ? A0 : (z == 1) ? A1 : A2;
  const unsigned short* W = (z == 0) ? W0 : (z == 1) ? W1 : W2;
  const float* bias = (z == 0) ? b0 : (z == 1) ? b1 : b2;
  unsigned short* C = (z == 0) ? C0 : (z == 1) ? C1 : C2;
  gemm_core(A, W, bias, C, (z == 2) ? 0 : 1, As, Bs);
}

__global__ __launch_bounds__(256) void gemm_o(const unsigned short* __restrict__ A,
                                              const unsigned short* __restrict__ W,
                                              const float* __restrict__ bias,
                                              float* __restrict__ C) {
  __shared__ unsigned short As[128 * 64];
  __shared__ unsigned short Bs[128 * 64];
  gemm_core(A, W, bias, C, 2, As, Bs);
}

// ---------------- V [B,L,1024](bf16) -> Vt [B,H,64,L](bf16) ----------------
__global__ __launch_bounds__(256) void transpose_v(const unsigned short* __restrict__ V,
                                                   unsigned short* __restrict__ Vt) {
  __shared__ unsigned short T[64][72];
  const int lt = blockIdx.x, h = blockIdx.y, b = blockIdx.z;
  const int t = threadIdx.x;
  const int r = t >> 2, c0 = (t & 3) * 16;
  const unsigned short* g = V + ((size_t)(b * LSEQ + lt * 64 + r) * DM + h * 64 + c0);
  *(uint4*)&T[r][c0] = *(const uint4*)g;
  *(uint4*)&T[r][c0 + 8] = *(const uint4*)(g + 8);
  __syncthreads();
  const int d = t >> 2, l0 = (t & 3) * 16;
  union { unsigned short u[16]; uint4 v[2]; } o;
#pragma unroll
  for (int j = 0; j < 16; ++j) o.u[j] = T[l0 + j][d];
  unsigned short* og = Vt + ((size_t)((b * NH + h) * HD + d) * LSEQ + lt * 64 + l0);
  ((uint4*)og)[0] = o.v[0];
  ((uint4*)og)[1] = o.v[1];
}

// ---------------- fused cosine attention ----------------
// Scores are bounded: |scale * cos_sim| <= ~22.3, so exp2 never overflows ->
// no online-max tracking needed. Pass 1: sum of exp. Pass 2: recompute, write
// attn (f32, NT, wave-contiguous), accumulate PV.
__global__ __launch_bounds__(256) void attn_kernel(
    const unsigned short* __restrict__ Qn, const unsigned short* __restrict__ Kn,
    const unsigned short* __restrict__ Vt, const int* __restrict__ mask,
    const float* __restrict__ scale_p, float* __restrict__ attn_out,
    unsigned short* __restrict__ ctx) {
  // PQs: pass 1 = Qs [64 rows x 128B] swizzled; pass 2 = Ps [64 rows x 256B] swizzled
  __shared__ unsigned short PQs[64 * 128];
  __shared__ unsigned short Ks[128 * 64];   // [key][d] swizzled, 128B rows
  __shared__ unsigned short Vs[64 * 128];   // [d][key] swizzled, 256B rows
  const int qt = blockIdx.x, h = blockIdx.y, b = blockIdx.z;
  const int t = threadIdx.x, lane = t & 63, wid = t >> 6;
  const int lq = lane >> 4, lr = lane & 15;
  const int wq = wid * 16;
  const float k2 = scale_p[0] * 1.4426950408889634f;  // fold log2(e)

  const unsigned short* Qg = Qn + ((size_t)(b * LSEQ + qt * 64) * DM + h * HD);
  const unsigned short* Kg = Kn + ((size_t)b * LSEQ * DM + h * HD);
  const unsigned short* Vg = Vt + (size_t)(b * NH + h) * HD * LSEQ;
  float* attn_g = attn_out + ((size_t)((b * NH + h) * LSEQ + qt * 64)) * LSEQ;
  const int* mg = mask + b * LSEQ;

  auto stageK = [&](int k0) {
#pragma unroll
    for (int i = 0; i < 4; ++i) {
      int chunk = i * 256 + t;
      int row = chunk >> 3, j = chunk & 7;
      async16(Kg + (size_t)(k0 + row) * DM + (j ^ (row & 7)) * 8, (char*)Ks + chunk * 16);
    }
  };
  auto stageV = [&](int k0) {
#pragma unroll
    for (int i = 0; i < 4; ++i) {
      int chunk = i * 256 + t;
      int row = chunk >> 4, j = chunk & 15;
      async16(Vg + (size_t)row * LSEQ + k0 + (j ^ (row & 7)) * 8, (char*)Vs + chunk * 16);
    }
  };

  // stage Q (into PQs) + K tile 0
#pragma unroll
  for (int i = 0; i < 2; ++i) {
    int chunk = i * 256 + t;
    int row = chunk >> 3, j = chunk & 7;
    async16(Qg + (size_t)row * DM + (j ^ (row & 7)) * 8, (char*)PQs + chunk * 16);
  }
  stageK(0);

  bf16x8 qa[2];
  float rsum[4] = {0.f, 0.f, 0.f, 0.f};

  auto qk_tile = [&](f32x4 (&c)[8]) {
#pragma unroll
    for (int nf = 0; nf < 8; ++nf) {
      int row = nf * 16 + lr;
      bf16x8 k0f = lds_frag_swz<128>(Ks, row, lq * 16);
      bf16x8 k1f = lds_frag_swz<128>(Ks, row, 64 + lq * 16);
      f32x4 z = (f32x4){0.f, 0.f, 0.f, 0.f};
      z = __builtin_amdgcn_mfma_f32_16x16x32_bf16(qa[0], k0f, z, 0, 0, 0);
      z = __builtin_amdgcn_mfma_f32_16x16x32_bf16(qa[1], k1f, z, 0, 0, 0);
      c[nf] = z;
    }
  };

  // ---- pass 1: denominators ----
  for (int kt = 0; kt < LSEQ / 128; ++kt) {
    __syncthreads();
    if (kt == 0) {
      int row = wq + lr;
      qa[0] = lds_frag_swz<128>(PQs, row, lq * 16);
      qa[1] = lds_frag_swz<128>(PQs, row, 64 + lq * 16);
    }
    f32x4 c[8];
    qk_tile(c);
    __syncthreads();
    if (kt + 1 < LSEQ / 128) stageK((kt + 1) * 128);
#pragma unroll
    for (int nf = 0; nf < 8; ++nf) {
      int mv = mg[kt * 128 + nf * 16 + lr];
#pragma unroll
      for (int r = 0; r < 4; ++r) {
        float p = exp2f(c[nf][r] * k2);
        rsum[r] += mv ? p : 0.f;
      }
    }
  }
  stageK(0);
  stageV(0);
  // merge across the 16 column-lanes (sum only)
#pragma unroll
  for (int off = 1; off < 16; off <<= 1)
#pragma unroll
    for (int r = 0; r < 4; ++r) rsum[r] += __shfl_xor(rsum[r], off, 64);
  float sinv[4];
#pragma unroll
  for (int r = 0; r < 4; ++r) sinv[r] = 1.0f / fmaxf(rsum[r], 1e-30f);

  // ---- pass 2: recompute scores, write attn, accumulate PV ----
  f32x4 opv[4];
#pragma unroll
  for (int nf = 0; nf < 4; ++nf) opv[nf] = (f32x4){0.f, 0.f, 0.f, 0.f};
  unsigned short* Ps = PQs;
  for (int kt = 0; kt < LSEQ / 128; ++kt) {
    __syncthreads();  // K,V staged
    f32x4 c[8];
    qk_tile(c);
#pragma unroll
    for (int nf = 0; nf < 8; ++nf) {
      int mv = mg[kt * 128 + nf * 16 + lr];
#pragma unroll
      for (int r = 0; r < 4; ++r) {
        float p = mv ? exp2f(c[nf][r] * k2) * sinv[r] : 0.f;
        lds_store16_swz(Ps, wq + lq * 4 + r, nf * 16 + lr, bf16r(p));
      }
    }
    __syncthreads();  // Ps visible; Ks reads done
    if (kt + 1 < LSEQ / 128) stageK((kt + 1) * 128);
    // wave-contiguous attn store: lane -> 32B contiguous, 16 lanes -> 512B row
    {
      int rr = t >> 4, c8 = (t & 15) * 8;
      float* og = attn_g + kt * 128 + c8;
#pragma unroll
      for (int gi = 0; gi < 4; ++gi) {
        int row = gi * 16 + rr;
        bf16x8 p8 = lds_frag_swz<256>(Ps, row, c8 * 2);
        f32x4 f0, f1;
        f0[0] = bf16f((unsigned short)p8[0]); f0[1] = bf16f((unsigned short)p8[1]);
        f0[2] = bf16f((unsigned short)p8[2]); f0[3] = bf16f((unsigned short)p8[3]);
        f1[0] = bf16f((unsigned short)p8[4]); f1[1] = bf16f((unsigned short)p8[5]);
        f1[2] = bf16f((unsigned short)p8[6]); f1[3] = bf16f((unsigned short)p8[7]);
        float* rp = og + (size_t)row * LSEQ;
        __builtin_nontemporal_store(f0, (f32x4*)rp);
        __builtin_nontemporal_store(f1, (f32x4*)(rp + 4));
      }
    }
    // PV: ctx[q][d] += P[q][k] * Vt[d][k]
#pragma unroll
    for (int ks = 0; ks < 4; ++ks) {
      bf16x8 pa = lds_frag_swz<256>(Ps, wq + lr, ks * 64 + lq * 16);
#pragma unroll
      for (int nf = 0; nf < 4; ++nf) {
        bf16x8 vb = lds_frag_swz<256>(Vs, nf * 16 + lr, ks * 64 + lq * 16);
        opv[nf] = __builtin_amdgcn_mfma_f32_16x16x32_bf16(pa, vb, opv[nf], 0, 0, 0);
      }
    }
    __syncthreads();  // Ps/Vs reads done
    if (kt + 1 < LSEQ / 128) stageV((kt + 1) * 128);
  }
#pragma unroll
  for (int nf = 0; nf < 4; ++nf)
#pragma unroll
    for (int r = 0; r < 4; ++r) {
      int q = wq + lq * 4 + r;
      int d = nf * 16 + lr;
      ctx[(size_t)(b * LSEQ + qt * 64 + q) * DM + h * HD + d] = bf16r(opv[nf][r]);
    }
}

extern "C" void kernel_launch(void* const* d_in, const int* in_sizes, int n_in,
                              void* d_out, int out_size, void* d_ws, size_t ws_size,
                              hipStream_t stream) {
  const float* query = (const float*)d_in[0];
  const float* key_ = (const float*)d_in[1];
  const float* value = (const float*)d_in[2];
  const int* mask = (const int*)d_in[3];
  const float* Wq = (const float*)d_in[4];
  const float* bq = (const float*)d_in[5];
  const float* Wk = (const float*)d_in[6];
  const float* bk = (const float*)d_in[7];
  const float* Wv = (const float*)d_in[8];
  const float* bv = (const float*)d_in[9];
  const float* Wo = (const float*)d_in[10];
  const float* bo = (const float*)d_in[11];
  const float* scale = (const float*)d_in[12];

  char* ws = (char*)d_ws;
  const size_t XB = 8388608;   // 4Mi bf16
  const size_t WB = 2097152;   // 1Mi bf16
  unsigned short* qb = (unsigned short*)(ws);
  unsigned short* kb = (unsigned short*)(ws + XB);
  unsigned short* vb = (unsigned short*)(ws + 2 * XB);
  unsigned short* wqb = (unsigned short*)(ws + 3 * XB);
  unsigned short* wkb = (unsigned short*)(ws + 3 * XB + WB);
  unsigned short* wvb = (unsigned short*)(ws + 3 * XB + 2 * WB);
  unsigned short* wob = (unsigned short*)(ws + 3 * XB + 3 * WB);
  unsigned short* Qnb = (unsigned short*)(ws + 3 * XB + 4 * WB);
  unsigned short* Knb = (unsigned short*)(ws + 4 * XB + 4 * WB);
  unsigned short* Vb = (unsigned short*)(ws + 5 * XB + 4 * WB);
  unsigned short* Vtb = (unsigned short*)(ws + 6 * XB + 4 * WB);
  unsigned short* ctxb = (unsigned short*)(ws + 7 * XB + 4 * WB);

  cvt3<<<dim3(2048, 3), 256, 0, stream>>>(query, key_, value, qb, kb, vb, 524288);
  cvt4<<<dim3(512, 4), 256, 0, stream>>>(Wq, Wk, Wv, Wo, wqb, wkb, wvb, wob, 131072);

  gemm_qkv<<<dim3(32, 8, 3), 256, 0, stream>>>(qb, kb, vb, wqb, wkb, wvb, bq, bk, bv,
                                               Qnb, Knb, Vb);
  transpose_v<<<dim3(32, NH, 2), 256, 0, stream>>>(Vb, Vtb);

  float* attn_out = (float*)d_out + 4194304;
  attn_kernel<<<dim3(32, NH, 2), 256, 0, stream>>>(Qnb, Knb, Vtb, mask, scale, attn_out, ctxb);

  gemm_o<<<dim3(32, 8), 256, 0, stream>>>(ctxb, wob, bo, (float*)d_out);
}

// Round 4
// 287.872 us; speedup vs baseline: 1.6763x; 1.0131x over previous
//
#include <hip/hip_runtime.h>
#include <hip/hip_bf16.h>
#include <stdint.h>

typedef __attribute__((ext_vector_type(8))) short bf16x8;
typedef __attribute__((ext_vector_type(4))) float f32x4;

#define LSEQ 2048
#define DM 1024
#define NH 16
#define HD 64

__device__ __forceinline__ unsigned short bf16r(float f) {
  unsigned u = __builtin_bit_cast(unsigned, f);
  u = (u + 0x7FFFu + ((u >> 16) & 1u)) >> 16;
  return (unsigned short)u;
}
__device__ __forceinline__ float bf16f(unsigned short h) {
  unsigned u = ((unsigned)h) << 16;
  return __builtin_bit_cast(float, u);
}
__device__ __forceinline__ unsigned cvt_pk_bf16(float a, float b) {
  unsigned r;
  asm("v_cvt_pk_bf16_f32 %0, %1, %2" : "=v"(r) : "v"(a), "v"(b));
  return r;
}

__device__ __forceinline__ void async16(const void* g, void* l) {
  __builtin_amdgcn_global_load_lds(
      (const __attribute__((address_space(1))) unsigned int*)g,
      (__attribute__((address_space(3))) unsigned int*)l, 16, 0, 0);
}

// swizzled ds_read_b128 from a 128B-row LDS tile (byte ^= (row&7)<<4)
__device__ __forceinline__ bf16x8 lds_frag_swz(const unsigned short* base, int row, int colbyte) {
  int addr = row * 128 + colbyte;
  addr ^= ((row & 7) << 4);
  return *(const bf16x8*)((const char*)base + addr);
}
// swizzled ds_read_b128 from a 256B-row LDS tile (byte ^= (row&15)<<4) — conflict-free
__device__ __forceinline__ bf16x8 lds_frag_swzV(const unsigned short* base, int row, int colbyte) {
  int addr = row * 256 + colbyte;
  addr ^= ((row & 15) << 4);
  return *(const bf16x8*)((const char*)base + addr);
}

// ---------------- f32 -> bf16 converts (fused multi-tensor) ----------------
__global__ __launch_bounds__(256) void cvt3(const float* __restrict__ s0,
                                            const float* __restrict__ s1,
                                            const float* __restrict__ s2,
                                            unsigned short* __restrict__ d0,
                                            unsigned short* __restrict__ d1,
                                            unsigned short* __restrict__ d2, int n8) {
  int y = blockIdx.y;
  const float* s = (y == 0) ? s0 : (y == 1) ? s1 : s2;
  unsigned short* d = (y == 0) ? d0 : (y == 1) ? d1 : d2;
  int i = blockIdx.x * 256 + threadIdx.x;
  if (i >= n8) return;
  const float4* sp = (const float4*)s;
  float4 a = sp[2 * i], b = sp[2 * i + 1];
  union { unsigned short u[8]; uint4 v; } r;
  r.u[0] = bf16r(a.x); r.u[1] = bf16r(a.y); r.u[2] = bf16r(a.z); r.u[3] = bf16r(a.w);
  r.u[4] = bf16r(b.x); r.u[5] = bf16r(b.y); r.u[6] = bf16r(b.z); r.u[7] = bf16r(b.w);
  ((uint4*)d)[i] = r.v;
}
__global__ __launch_bounds__(256) void cvt4(const float* __restrict__ s0,
                                            const float* __restrict__ s1,
                                            const float* __restrict__ s2,
                                            const float* __restrict__ s3,
                                            unsigned short* __restrict__ d0,
                                            unsigned short* __restrict__ d1,
                                            unsigned short* __restrict__ d2,
                                            unsigned short* __restrict__ d3, int n8) {
  int y = blockIdx.y;
  const float* s = (y == 0) ? s0 : (y == 1) ? s1 : (y == 2) ? s2 : s3;
  unsigned short* d = (y == 0) ? d0 : (y == 1) ? d1 : (y == 2) ? d2 : d3;
  int i = blockIdx.x * 256 + threadIdx.x;
  if (i >= n8) return;
  const float4* sp = (const float4*)s;
  float4 a = sp[2 * i], b = sp[2 * i + 1];
  union { unsigned short u[8]; uint4 v; } r;
  r.u[0] = bf16r(a.x); r.u[1] = bf16r(a.y); r.u[2] = bf16r(a.z); r.u[3] = bf16r(a.w);
  r.u[4] = bf16r(b.x); r.u[5] = bf16r(b.y); r.u[6] = bf16r(b.z); r.u[7] = bf16r(b.w);
  ((uint4*)d)[i] = r.v;
}

// ---------------- GEMM core: C[4096,1024] = A @ W^T + bias ----------------
// MODE 0: bf16 out; 1: bf16 + per-64-col L2 norm; 2: f32 out; 3: bf16 out transposed to Vt[B,H,64,L]
template <int MODE>
__device__ __forceinline__ void gemm_core(const unsigned short* __restrict__ A,
                                          const unsigned short* __restrict__ Bw,
                                          const float* __restrict__ bias,
                                          void* __restrict__ Cout,
                                          unsigned short* As, unsigned short* Bs) {
  const int t = threadIdx.x, lane = t & 63, wid = t >> 6;
  const int mt = blockIdx.x, nt = blockIdx.y;
  const int wm = (wid >> 1) * 64, wn = (wid & 1) * 64;
  const int lq = lane >> 4, lr = lane & 15;

  f32x4 acc[4][4];
#pragma unroll
  for (int i = 0; i < 4; ++i)
#pragma unroll
    for (int j = 0; j < 4; ++j) acc[i][j] = (f32x4){0.f, 0.f, 0.f, 0.f};

  auto stage = [&](int k0) {
#pragma unroll
    for (int i = 0; i < 4; ++i) {
      int chunk = i * 256 + t;
      int row = chunk >> 3, j = chunk & 7;
      int sj = j ^ (row & 7);
      async16(A + (size_t)(mt * 128 + row) * DM + k0 + sj * 8, (char*)As + chunk * 16);
    }
#pragma unroll
    for (int i = 0; i < 4; ++i) {
      int chunk = i * 256 + t;
      int row = chunk >> 3, j = chunk & 7;
      int sj = j ^ (row & 7);
      async16(Bw + (size_t)(nt * 128 + row) * DM + k0 + sj * 8, (char*)Bs + chunk * 16);
    }
  };

  stage(0);
  for (int kt = 0; kt < DM / 64; ++kt) {
    __syncthreads();
    bf16x8 af[4][2], bfr[4][2];
#pragma unroll
    for (int mf = 0; mf < 4; ++mf) {
      int row = wm + mf * 16 + lr;
#pragma unroll
      for (int ks = 0; ks < 2; ++ks)
        af[mf][ks] = lds_frag_swz(As, row, ks * 64 + lq * 16);
    }
#pragma unroll
    for (int nf = 0; nf < 4; ++nf) {
      int row = wn + nf * 16 + lr;
#pragma unroll
      for (int ks = 0; ks < 2; ++ks)
        bfr[nf][ks] = lds_frag_swz(Bs, row, ks * 64 + lq * 16);
    }
    __syncthreads();
    if (kt + 1 < DM / 64) stage((kt + 1) * 64);
#pragma unroll
    for (int ks = 0; ks < 2; ++ks)
#pragma unroll
      for (int mf = 0; mf < 4; ++mf)
#pragma unroll
        for (int nf = 0; nf < 4; ++nf)
          acc[mf][nf] = __builtin_amdgcn_mfma_f32_16x16x32_bf16(af[mf][ks], bfr[nf][ks],
                                                                acc[mf][nf], 0, 0, 0);
  }

  const int gn0 = nt * 128 + wn;
  float bv[4];
#pragma unroll
  for (int nf = 0; nf < 4; ++nf) bv[nf] = bias[gn0 + nf * 16 + lr];
#pragma unroll
  for (int mf = 0; mf < 4; ++mf) {
    float v[4][4];
#pragma unroll
    for (int nf = 0; nf < 4; ++nf)
#pragma unroll
      for (int r = 0; r < 4; ++r) v[nf][r] = acc[mf][nf][r] + bv[nf];
    if (MODE == 1) {
#pragma unroll
      for (int r = 0; r < 4; ++r) {
        float ss = v[0][r] * v[0][r] + v[1][r] * v[1][r] + v[2][r] * v[2][r] + v[3][r] * v[3][r];
        ss += __shfl_xor(ss, 1, 64);
        ss += __shfl_xor(ss, 2, 64);
        ss += __shfl_xor(ss, 4, 64);
        ss += __shfl_xor(ss, 8, 64);
        float rn = 1.0f / fmaxf(sqrtf(ss), 1e-12f);
#pragma unroll
        for (int nf = 0; nf < 4; ++nf) v[nf][r] *= rn;
      }
    }
    const int gm0 = mt * 128 + wm + mf * 16 + lq * 4;
    if (MODE == 2) {
      float* C = (float*)Cout;
#pragma unroll
      for (int r = 0; r < 4; ++r)
#pragma unroll
        for (int nf = 0; nf < 4; ++nf)
          C[(size_t)(gm0 + r) * DM + gn0 + nf * 16 + lr] = v[nf][r];
    } else if (MODE == 3) {
      // write transposed: Vt[(b*NH+h)*HD + d][l], rows l = gm0..gm0+3 contiguous
      unsigned short* Vt = (unsigned short*)Cout;
      const int bb = gm0 >> 11, ll = gm0 & 2047;
#pragma unroll
      for (int nf = 0; nf < 4; ++nf) {
        int col = gn0 + nf * 16 + lr;
        int hh = col >> 6, dd = col & 63;
        ushort4 o;
        o.x = bf16r(v[nf][0]); o.y = bf16r(v[nf][1]);
        o.z = bf16r(v[nf][2]); o.w = bf16r(v[nf][3]);
        *(ushort4*)&Vt[(size_t)((bb * NH + hh) * HD + dd) * LSEQ + ll] = o;
      }
    } else {
      unsigned short* C = (unsigned short*)Cout;
#pragma unroll
      for (int r = 0; r < 4; ++r)
#pragma unroll
        for (int nf = 0; nf < 4; ++nf)
          C[(size_t)(gm0 + r) * DM + gn0 + nf * 16 + lr] = bf16r(v[nf][r]);
    }
  }
}

__global__ __launch_bounds__(256) void gemm_qkv(
    const unsigned short* __restrict__ A0, const unsigned short* __restrict__ A1,
    const unsigned short* __restrict__ A2, const unsigned short* __restrict__ W0,
    const unsigned short* __restrict__ W1, const unsigned short* __restrict__ W2,
    const float* __restrict__ b0, const float* __restrict__ b1, const float* __restrict__ b2,
    unsigned short* __restrict__ C0, unsigned short* __restrict__ C1,
    unsigned short* __restrict__ C2) {
  __shared__ unsigned short As[128 * 64];
  __shared__ unsigned short Bs[128 * 64];
  int z = blockIdx.z;
  if (z == 0) gemm_core<1>(A0, W0, b0, C0, As, Bs);
  else if (z == 1) gemm_core<1>(A1, W1, b1, C1, As, Bs);
  else gemm_core<3>(A2, W2, b2, C2, As, Bs);  // V -> Vt directly
}

__global__ __launch_bounds__(256) void gemm_o(const unsigned short* __restrict__ A,
                                              const unsigned short* __restrict__ W,
                                              const float* __restrict__ bias,
                                              float* __restrict__ C) {
  __shared__ unsigned short As[128 * 64];
  __shared__ unsigned short Bs[128 * 64];
  gemm_core<2>(A, W, bias, C, As, Bs);
}

// ---------------- fused cosine attention (swapped QK^T: S^T in registers) ----------------
// Scores bounded (|scale*cos| <= ~22.3) -> no max tracking. Pass 1: denominators.
// Pass 2: recompute, NT-store attn directly from registers, repack P via cvt_pk +
// bpermute for PV (no P LDS buffer). LDS = 36 KB -> 4 blocks/CU.
__global__ __launch_bounds__(256, 4) void attn_kernel(
    const unsigned short* __restrict__ Qn, const unsigned short* __restrict__ Kn,
    const unsigned short* __restrict__ Vt, const int* __restrict__ mask,
    const float* __restrict__ scale_p, float* __restrict__ attn_out,
    unsigned short* __restrict__ ctx) {
  __shared__ unsigned short QVs[64 * 128];  // pass1: Q [64q][128B] (first 8KB); pass2: V [64d][256B]
  __shared__ unsigned short Ks[128 * 64];   // [128k][128B], swizzled (row&7)
  __shared__ unsigned short Ms[2048];       // mask as bf16 {0,1}
  const int qt = blockIdx.x, h = blockIdx.y, b = blockIdx.z;
  const int t = threadIdx.x, lane = t & 63, wid = t >> 6;
  const int lq = lane >> 4, lr = lane & 15;
  const int wq = wid * 16;
  const float k2 = scale_p[0] * 1.4426950408889634f;

  const unsigned short* Qg = Qn + ((size_t)(b * LSEQ + qt * 64) * DM + h * HD);
  const unsigned short* Kg = Kn + ((size_t)b * LSEQ * DM + h * HD);
  const unsigned short* Vg = Vt + (size_t)(b * NH + h) * HD * LSEQ;
  float* attn_g = attn_out + ((size_t)((b * NH + h) * LSEQ + qt * 64)) * LSEQ;
  const int* mg = mask + b * LSEQ;

  auto stageK = [&](int k0) {
#pragma unroll
    for (int i = 0; i < 4; ++i) {
      int chunk = i * 256 + t;
      int row = chunk >> 3, j = chunk & 7;
      async16(Kg + (size_t)(k0 + row) * DM + (j ^ (row & 7)) * 8, (char*)Ks + chunk * 16);
    }
  };
  auto stageV = [&](int k0) {
#pragma unroll
    for (int i = 0; i < 4; ++i) {
      int chunk = i * 256 + t;
      int row = chunk >> 4, j = chunk & 15;
      async16(Vg + (size_t)row * LSEQ + k0 + (j ^ (row & 15)) * 8, (char*)QVs + chunk * 16);
    }
  };

  // stage mask -> Ms (bf16 0/1)
  {
    const int4* mp = (const int4*)mg;
    int4 m0 = mp[t * 2], m1 = mp[t * 2 + 1];
    union { unsigned short u[8]; uint4 v; } mo;
    mo.u[0] = m0.x ? 0x3F80 : 0; mo.u[1] = m0.y ? 0x3F80 : 0;
    mo.u[2] = m0.z ? 0x3F80 : 0; mo.u[3] = m0.w ? 0x3F80 : 0;
    mo.u[4] = m1.x ? 0x3F80 : 0; mo.u[5] = m1.y ? 0x3F80 : 0;
    mo.u[6] = m1.z ? 0x3F80 : 0; mo.u[7] = m1.w ? 0x3F80 : 0;
    ((uint4*)Ms)[t] = mo.v;
  }
  // stage Q (into QVs, 8KB) + K tile 0
#pragma unroll
  for (int i = 0; i < 2; ++i) {
    int chunk = i * 256 + t;
    int row = chunk >> 3, j = chunk & 7;
    async16(Qg + (size_t)row * DM + (j ^ (row & 7)) * 8, (char*)QVs + chunk * 16);
  }
  stageK(0);

  bf16x8 qa[2];
  float rsum = 0.f;

  // ---- pass 1: denominators ----
  for (int kt = 0; kt < LSEQ / 128; ++kt) {
    __syncthreads();
    if (kt == 0) {
      qa[0] = lds_frag_swz(QVs, wq + lr, lq * 16);
      qa[1] = lds_frag_swz(QVs, wq + lr, 64 + lq * 16);
    }
#pragma unroll
    for (int nf = 0; nf < 8; ++nf) {
      bf16x8 k0f = lds_frag_swz(Ks, nf * 16 + lr, lq * 16);
      bf16x8 k1f = lds_frag_swz(Ks, nf * 16 + lr, 64 + lq * 16);
      f32x4 z = (f32x4){0.f, 0.f, 0.f, 0.f};
      z = __builtin_amdgcn_mfma_f32_16x16x32_bf16(k0f, qa[0], z, 0, 0, 0);
      z = __builtin_amdgcn_mfma_f32_16x16x32_bf16(k1f, qa[1], z, 0, 0, 0);
      ushort4 m4 = *(const ushort4*)&Ms[kt * 128 + nf * 16 + lq * 4];
      rsum += exp2f(z[0] * k2) * bf16f(m4.x);
      rsum += exp2f(z[1] * k2) * bf16f(m4.y);
      rsum += exp2f(z[2] * k2) * bf16f(m4.z);
      rsum += exp2f(z[3] * k2) * bf16f(m4.w);
    }
    __syncthreads();
    if (kt + 1 < LSEQ / 128) stageK((kt + 1) * 128);
  }
  rsum += __shfl_xor(rsum, 16, 64);
  rsum += __shfl_xor(rsum, 32, 64);
  const float sinv = 1.0f / fmaxf(rsum, 1e-30f);

  // ---- pass 2: recompute, store attn, accumulate PV ----
  stageK(0);
  stageV(0);
  f32x4 opv[4];
#pragma unroll
  for (int nf = 0; nf < 4; ++nf) opv[nf] = (f32x4){0.f, 0.f, 0.f, 0.f};
  const int s0 = (lq & 1) * 32 + lr, s1 = s0 + 16;
  const bool hi = (lq >> 1) != 0;

  for (int kt = 0; kt < LSEQ / 128; ++kt) {
    __syncthreads();  // K,V tile staged
    unsigned pw[16];
#pragma unroll
    for (int nf = 0; nf < 8; ++nf) {
      bf16x8 k0f = lds_frag_swz(Ks, nf * 16 + lr, lq * 16);
      bf16x8 k1f = lds_frag_swz(Ks, nf * 16 + lr, 64 + lq * 16);
      f32x4 z = (f32x4){0.f, 0.f, 0.f, 0.f};
      z = __builtin_amdgcn_mfma_f32_16x16x32_bf16(k0f, qa[0], z, 0, 0, 0);
      z = __builtin_amdgcn_mfma_f32_16x16x32_bf16(k1f, qa[1], z, 0, 0, 0);
      ushort4 m4 = *(const ushort4*)&Ms[kt * 128 + nf * 16 + lq * 4];
      float p0 = exp2f(z[0] * k2) * bf16f(m4.x) * sinv;
      float p1 = exp2f(z[1] * k2) * bf16f(m4.y) * sinv;
      float p2 = exp2f(z[2] * k2) * bf16f(m4.z) * sinv;
      float p3 = exp2f(z[3] * k2) * bf16f(m4.w) * sinv;
      f32x4 st = (f32x4){p0, p1, p2, p3};
      __builtin_nontemporal_store(
          st, (f32x4*)(attn_g + (size_t)(wq + lr) * LSEQ + kt * 128 + nf * 16 + lq * 4));
      pw[nf * 2] = cvt_pk_bf16(p0, p1);
      pw[nf * 2 + 1] = cvt_pk_bf16(p2, p3);
    }
    // PV: repack S^T registers into B-fragments via bpermute, mfma with Vt
#pragma unroll
    for (int ks = 0; ks < 4; ++ks) {
      unsigned a0 = pw[4 * ks], a1 = pw[4 * ks + 1];
      unsigned b0 = pw[4 * ks + 2], b1 = pw[4 * ks + 3];
      unsigned ua0 = __shfl((int)a0, s0, 64), ua1 = __shfl((int)a1, s0, 64);
      unsigned ua2 = __shfl((int)a0, s1, 64), ua3 = __shfl((int)a1, s1, 64);
      unsigned ub0 = __shfl((int)b0, s0, 64), ub1 = __shfl((int)b1, s0, 64);
      unsigned ub2 = __shfl((int)b0, s1, 64), ub3 = __shfl((int)b1, s1, 64);
      union { unsigned w[4]; bf16x8 v; } pf;
      pf.w[0] = hi ? ub0 : ua0;
      pf.w[1] = hi ? ub1 : ua1;
      pf.w[2] = hi ? ub2 : ua2;
      pf.w[3] = hi ? ub3 : ua3;
#pragma unroll
      for (int nf = 0; nf < 4; ++nf) {
        bf16x8 vb = lds_frag_swzV(QVs, nf * 16 + lr, ks * 64 + lq * 16);
        opv[nf] = __builtin_amdgcn_mfma_f32_16x16x32_bf16(vb, pf.v, opv[nf], 0, 0, 0);
      }
    }
    __syncthreads();  // all reads of this tile done
    if (kt + 1 < LSEQ / 128) { stageK((kt + 1) * 128); stageV((kt + 1) * 128); }
  }
  // ctx store: opv[nf][r] -> q = wq+lr, d = nf*16+lq*4+r (4 consecutive d -> 8B stores)
#pragma unroll
  for (int nf = 0; nf < 4; ++nf) {
    ushort4 o;
    o.x = bf16r(opv[nf][0]); o.y = bf16r(opv[nf][1]);
    o.z = bf16r(opv[nf][2]); o.w = bf16r(opv[nf][3]);
    *(ushort4*)&ctx[(size_t)(b * LSEQ + qt * 64 + wq + lr) * DM + h * HD + nf * 16 + lq * 4] = o;
  }
}

extern "C" void kernel_launch(void* const* d_in, const int* in_sizes, int n_in,
                              void* d_out, int out_size, void* d_ws, size_t ws_size,
                              hipStream_t stream) {
  const float* query = (const float*)d_in[0];
  const float* key_ = (const float*)d_in[1];
  const float* value = (const float*)d_in[2];
  const int* mask = (const int*)d_in[3];
  const float* Wq = (const float*)d_in[4];
  const float* bq = (const float*)d_in[5];
  const float* Wk = (const float*)d_in[6];
  const float* bk = (const float*)d_in[7];
  const float* Wv = (const float*)d_in[8];
  const float* bv = (const float*)d_in[9];
  const float* Wo = (const float*)d_in[10];
  const float* bo = (const float*)d_in[11];
  const float* scale = (const float*)d_in[12];

  char* ws = (char*)d_ws;
  const size_t XB = 8388608;   // 4Mi bf16
  const size_t WB = 2097152;   // 1Mi bf16
  unsigned short* qb = (unsigned short*)(ws);
  unsigned short* kb = (unsigned short*)(ws + XB);
  unsigned short* vb = (unsigned short*)(ws + 2 * XB);
  unsigned short* wqb = (unsigned short*)(ws + 3 * XB);
  unsigned short* wkb = (unsigned short*)(ws + 3 * XB + WB);
  unsigned short* wvb = (unsigned short*)(ws + 3 * XB + 2 * WB);
  unsigned short* wob = (unsigned short*)(ws + 3 * XB + 3 * WB);
  unsigned short* Qnb = (unsigned short*)(ws + 3 * XB + 4 * WB);
  unsigned short* Knb = (unsigned short*)(ws + 4 * XB + 4 * WB);
  unsigned short* Vtb = (unsigned short*)(ws + 5 * XB + 4 * WB);
  unsigned short* ctxb = (unsigned short*)(ws + 6 * XB + 4 * WB);

  cvt3<<<dim3(2048, 3), 256, 0, stream>>>(query, key_, value, qb, kb, vb, 524288);
  cvt4<<<dim3(512, 4), 256, 0, stream>>>(Wq, Wk, Wv, Wo, wqb, wkb, wvb, wob, 131072);

  gemm_qkv<<<dim3(32, 8, 3), 256, 0, stream>>>(qb, kb, vb, wqb, wkb, wvb, bq, bk, bv,
                                               Qnb, Knb, Vtb);

  float* attn_out = (float*)d_out + 4194304;
  attn_kernel<<<dim3(32, NH, 2), 256, 0, stream>>>(Qnb, Knb, Vtb, mask, scale, attn_out, ctxb);

  gemm_o<<<dim3(32, 8), 256, 0, stream>>>(ctxb, wob, bo, (float*)d_out);
}

// Round 5
// 268.678 us; speedup vs baseline: 1.7961x; 1.0714x over previous
//
#include <hip/hip_runtime.h>
#include <hip/hip_bf16.h>
#include <stdint.h>

typedef __attribute__((ext_vector_type(8))) short bf16x8;
typedef __attribute__((ext_vector_type(4))) float f32x4;

#define LSEQ 2048
#define DM 1024
#define NH 16
#define HD 64

__device__ __forceinline__ unsigned short bf16r(float f) {
  unsigned u = __builtin_bit_cast(unsigned, f);
  u = (u + 0x7FFFu + ((u >> 16) & 1u)) >> 16;
  return (unsigned short)u;
}
__device__ __forceinline__ float bf16f(unsigned short h) {
  unsigned u = ((unsigned)h) << 16;
  return __builtin_bit_cast(float, u);
}
__device__ __forceinline__ unsigned cvt_pk_bf16(float a, float b) {
  unsigned r;
  asm("v_cvt_pk_bf16_f32 %0, %1, %2" : "=v"(r) : "v"(a), "v"(b));
  return r;
}

__device__ __forceinline__ void async16(const void* g, void* l) {
  __builtin_amdgcn_global_load_lds(
      (const __attribute__((address_space(1))) unsigned int*)g,
      (__attribute__((address_space(3))) unsigned int*)l, 16, 0, 0);
}

// swizzled ds_read_b128 from a 128B-row LDS tile (byte ^= (row&7)<<4)
__device__ __forceinline__ bf16x8 lds_frag_swz(const unsigned short* base, int row, int colbyte) {
  int addr = row * 128 + colbyte;
  addr ^= ((row & 7) << 4);
  return *(const bf16x8*)((const char*)base + addr);
}
// swizzled ds_read_b128 from a 256B-row LDS tile (byte ^= (row&15)<<4)
__device__ __forceinline__ bf16x8 lds_frag_swzV(const unsigned short* base, int row, int colbyte) {
  int addr = row * 256 + colbyte;
  addr ^= ((row & 15) << 4);
  return *(const bf16x8*)((const char*)base + addr);
}

// ---------------- f32 -> bf16 converts (fused multi-tensor) ----------------
__global__ __launch_bounds__(256) void cvt3(const float* __restrict__ s0,
                                            const float* __restrict__ s1,
                                            const float* __restrict__ s2,
                                            unsigned short* __restrict__ d0,
                                            unsigned short* __restrict__ d1,
                                            unsigned short* __restrict__ d2, int n8) {
  int y = blockIdx.y;
  const float* s = (y == 0) ? s0 : (y == 1) ? s1 : s2;
  unsigned short* d = (y == 0) ? d0 : (y == 1) ? d1 : d2;
  int i = blockIdx.x * 256 + threadIdx.x;
  if (i >= n8) return;
  const float4* sp = (const float4*)s;
  float4 a = sp[2 * i], b = sp[2 * i + 1];
  union { unsigned short u[8]; uint4 v; } r;
  r.u[0] = bf16r(a.x); r.u[1] = bf16r(a.y); r.u[2] = bf16r(a.z); r.u[3] = bf16r(a.w);
  r.u[4] = bf16r(b.x); r.u[5] = bf16r(b.y); r.u[6] = bf16r(b.z); r.u[7] = bf16r(b.w);
  ((uint4*)d)[i] = r.v;
}
__global__ __launch_bounds__(256) void cvt4(const float* __restrict__ s0,
                                            const float* __restrict__ s1,
                                            const float* __restrict__ s2,
                                            const float* __restrict__ s3,
                                            unsigned short* __restrict__ d0,
                                            unsigned short* __restrict__ d1,
                                            unsigned short* __restrict__ d2,
                                            unsigned short* __restrict__ d3, int n8) {
  int y = blockIdx.y;
  const float* s = (y == 0) ? s0 : (y == 1) ? s1 : (y == 2) ? s2 : s3;
  unsigned short* d = (y == 0) ? d0 : (y == 1) ? d1 : (y == 2) ? d2 : d3;
  int i = blockIdx.x * 256 + threadIdx.x;
  if (i >= n8) return;
  const float4* sp = (const float4*)s;
  float4 a = sp[2 * i], b = sp[2 * i + 1];
  union { unsigned short u[8]; uint4 v; } r;
  r.u[0] = bf16r(a.x); r.u[1] = bf16r(a.y); r.u[2] = bf16r(a.z); r.u[3] = bf16r(a.w);
  r.u[4] = bf16r(b.x); r.u[5] = bf16r(b.y); r.u[6] = bf16r(b.z); r.u[7] = bf16r(b.w);
  ((uint4*)d)[i] = r.v;
}

// ---------------- GEMM core: C[4096,1024] = A @ W^T + bias ----------------
template <int MODE>
__device__ __forceinline__ void gemm_core(const unsigned short* __restrict__ A,
                                          const unsigned short* __restrict__ Bw,
                                          const float* __restrict__ bias,
                                          void* __restrict__ Cout,
                                          unsigned short* As, unsigned short* Bs) {
  const int t = threadIdx.x, lane = t & 63, wid = t >> 6;
  const int mt = blockIdx.x, nt = blockIdx.y;
  const int wm = (wid >> 1) * 64, wn = (wid & 1) * 64;
  const int lq = lane >> 4, lr = lane & 15;

  f32x4 acc[4][4];
#pragma unroll
  for (int i = 0; i < 4; ++i)
#pragma unroll
    for (int j = 0; j < 4; ++j) acc[i][j] = (f32x4){0.f, 0.f, 0.f, 0.f};

  auto stage = [&](int k0) {
#pragma unroll
    for (int i = 0; i < 4; ++i) {
      int chunk = i * 256 + t;
      int row = chunk >> 3, j = chunk & 7;
      int sj = j ^ (row & 7);
      async16(A + (size_t)(mt * 128 + row) * DM + k0 + sj * 8, (char*)As + chunk * 16);
    }
#pragma unroll
    for (int i = 0; i < 4; ++i) {
      int chunk = i * 256 + t;
      int row = chunk >> 3, j = chunk & 7;
      int sj = j ^ (row & 7);
      async16(Bw + (size_t)(nt * 128 + row) * DM + k0 + sj * 8, (char*)Bs + chunk * 16);
    }
  };

  stage(0);
  for (int kt = 0; kt < DM / 64; ++kt) {
    __syncthreads();
    bf16x8 af[4][2], bfr[4][2];
#pragma unroll
    for (int mf = 0; mf < 4; ++mf) {
      int row = wm + mf * 16 + lr;
#pragma unroll
      for (int ks = 0; ks < 2; ++ks)
        af[mf][ks] = lds_frag_swz(As, row, ks * 64 + lq * 16);
    }
#pragma unroll
    for (int nf = 0; nf < 4; ++nf) {
      int row = wn + nf * 16 + lr;
#pragma unroll
      for (int ks = 0; ks < 2; ++ks)
        bfr[nf][ks] = lds_frag_swz(Bs, row, ks * 64 + lq * 16);
    }
    __syncthreads();
    if (kt + 1 < DM / 64) stage((kt + 1) * 64);
#pragma unroll
    for (int ks = 0; ks < 2; ++ks)
#pragma unroll
      for (int mf = 0; mf < 4; ++mf)
#pragma unroll
        for (int nf = 0; nf < 4; ++nf)
          acc[mf][nf] = __builtin_amdgcn_mfma_f32_16x16x32_bf16(af[mf][ks], bfr[nf][ks],
                                                                acc[mf][nf], 0, 0, 0);
  }

  const int gn0 = nt * 128 + wn;
  float bv[4];
#pragma unroll
  for (int nf = 0; nf < 4; ++nf) bv[nf] = bias[gn0 + nf * 16 + lr];
#pragma unroll
  for (int mf = 0; mf < 4; ++mf) {
    float v[4][4];
#pragma unroll
    for (int nf = 0; nf < 4; ++nf)
#pragma unroll
      for (int r = 0; r < 4; ++r) v[nf][r] = acc[mf][nf][r] + bv[nf];
    if (MODE == 1) {
#pragma unroll
      for (int r = 0; r < 4; ++r) {
        float ss = v[0][r] * v[0][r] + v[1][r] * v[1][r] + v[2][r] * v[2][r] + v[3][r] * v[3][r];
        ss += __shfl_xor(ss, 1, 64);
        ss += __shfl_xor(ss, 2, 64);
        ss += __shfl_xor(ss, 4, 64);
        ss += __shfl_xor(ss, 8, 64);
        float rn = 1.0f / fmaxf(sqrtf(ss), 1e-12f);
#pragma unroll
        for (int nf = 0; nf < 4; ++nf) v[nf][r] *= rn;
      }
    }
    const int gm0 = mt * 128 + wm + mf * 16 + lq * 4;
    if (MODE == 2) {
      float* C = (float*)Cout;
#pragma unroll
      for (int r = 0; r < 4; ++r)
#pragma unroll
        for (int nf = 0; nf < 4; ++nf)
          C[(size_t)(gm0 + r) * DM + gn0 + nf * 16 + lr] = v[nf][r];
    } else if (MODE == 3) {
      unsigned short* Vt = (unsigned short*)Cout;
      const int bb = gm0 >> 11, ll = gm0 & 2047;
#pragma unroll
      for (int nf = 0; nf < 4; ++nf) {
        int col = gn0 + nf * 16 + lr;
        int hh = col >> 6, dd = col & 63;
        ushort4 o;
        o.x = bf16r(v[nf][0]); o.y = bf16r(v[nf][1]);
        o.z = bf16r(v[nf][2]); o.w = bf16r(v[nf][3]);
        *(ushort4*)&Vt[(size_t)((bb * NH + hh) * HD + dd) * LSEQ + ll] = o;
      }
    } else {
      unsigned short* C = (unsigned short*)Cout;
#pragma unroll
      for (int r = 0; r < 4; ++r)
#pragma unroll
        for (int nf = 0; nf < 4; ++nf)
          C[(size_t)(gm0 + r) * DM + gn0 + nf * 16 + lr] = bf16r(v[nf][r]);
    }
  }
}

__global__ __launch_bounds__(256) void gemm_qkv(
    const unsigned short* __restrict__ A0, const unsigned short* __restrict__ A1,
    const unsigned short* __restrict__ A2, const unsigned short* __restrict__ W0,
    const unsigned short* __restrict__ W1, const unsigned short* __restrict__ W2,
    const float* __restrict__ b0, const float* __restrict__ b1, const float* __restrict__ b2,
    unsigned short* __restrict__ C0, unsigned short* __restrict__ C1,
    unsigned short* __restrict__ C2) {
  __shared__ unsigned short As[128 * 64];
  __shared__ unsigned short Bs[128 * 64];
  int z = blockIdx.z;
  if (z == 0) gemm_core<1>(A0, W0, b0, C0, As, Bs);
  else if (z == 1) gemm_core<1>(A1, W1, b1, C1, As, Bs);
  else gemm_core<3>(A2, W2, b2, C2, As, Bs);
}

__global__ __launch_bounds__(256) void gemm_o(const unsigned short* __restrict__ A,
                                              const unsigned short* __restrict__ W,
                                              const float* __restrict__ bias,
                                              float* __restrict__ C) {
  __shared__ unsigned short As[128 * 64];
  __shared__ unsigned short Bs[128 * 64];
  gemm_core<2>(A, W, bias, C, As, Bs);
}

// ---------------- fused cosine attention, 2x2 wave split ----------------
// Wave (qg,kg) owns q in [qg*32,+32), keys in [kg*64,+64) of each 128-key tile.
// Q in registers; per-tile LDS reads: 8 K-frags + 8 V-frags per wave.
// Scores bounded (|scale*cos| <= ~22.3) -> no max tracking.
__global__ __launch_bounds__(256, 4) void attn_kernel(
    const unsigned short* __restrict__ Qn, const unsigned short* __restrict__ Kn,
    const unsigned short* __restrict__ Vt, const int* __restrict__ mask,
    const float* __restrict__ scale_p, float* __restrict__ attn_out,
    unsigned short* __restrict__ ctx) {
  __shared__ unsigned short QVs[64 * 128];  // Q [64q][128B] (8KB) then V [64d][256B] (16KB)
  __shared__ unsigned short Ks[128 * 64];   // [128k][128B] 16KB; f32 ctx scratch at end
  __shared__ unsigned short Ms[2048];       // mask as bf16 {0,1}, 4KB
  __shared__ float Rs[2][2][32];            // rowsum partials [qg][kg][q]

  // XCD-chunked swizzle: 1024 blocks, 128 per XCD -> 4 (b,h) K/V panels per XCD L2
  const int raw = blockIdx.x;
  const int swz = (raw & 7) * 128 + (raw >> 3);
  const int qt = swz & 31, h = (swz >> 5) & 15, b = swz >> 9;

  const int t = threadIdx.x, lane = t & 63, wid = t >> 6;
  const int lq = lane >> 4, lr = lane & 15;
  const int qg = wid >> 1, kg = wid & 1;
  const float k2 = scale_p[0] * 1.4426950408889634f;

  const unsigned short* Qg = Qn + ((size_t)(b * LSEQ + qt * 64) * DM + h * HD);
  const unsigned short* Kg = Kn + ((size_t)b * LSEQ * DM + h * HD);
  const unsigned short* Vg = Vt + (size_t)(b * NH + h) * HD * LSEQ;
  float* attn_g = attn_out + ((size_t)((b * NH + h) * LSEQ + qt * 64)) * LSEQ;
  const int* mg = mask + b * LSEQ;

  auto stageK = [&](int k0) {
#pragma unroll
    for (int i = 0; i < 4; ++i) {
      int chunk = i * 256 + t;
      int row = chunk >> 3, j = chunk & 7;
      async16(Kg + (size_t)(k0 + row) * DM + (j ^ (row & 7)) * 8, (char*)Ks + chunk * 16);
    }
  };
  auto stageV = [&](int k0) {
#pragma unroll
    for (int i = 0; i < 4; ++i) {
      int chunk = i * 256 + t;
      int row = chunk >> 4, j = chunk & 15;
      async16(Vg + (size_t)row * LSEQ + k0 + (j ^ (row & 15)) * 8, (char*)QVs + chunk * 16);
    }
  };

  // mask -> Ms (bf16 0/1)
  {
    const int4* mp = (const int4*)mg;
    int4 m0 = mp[t * 2], m1 = mp[t * 2 + 1];
    union { unsigned short u[8]; uint4 v; } mo;
    mo.u[0] = m0.x ? 0x3F80 : 0; mo.u[1] = m0.y ? 0x3F80 : 0;
    mo.u[2] = m0.z ? 0x3F80 : 0; mo.u[3] = m0.w ? 0x3F80 : 0;
    mo.u[4] = m1.x ? 0x3F80 : 0; mo.u[5] = m1.y ? 0x3F80 : 0;
    mo.u[6] = m1.z ? 0x3F80 : 0; mo.u[7] = m1.w ? 0x3F80 : 0;
    ((uint4*)Ms)[t] = mo.v;
  }
  // stage Q + K tile 0
#pragma unroll
  for (int i = 0; i < 2; ++i) {
    int chunk = i * 256 + t;
    int row = chunk >> 3, j = chunk & 7;
    async16(Qg + (size_t)row * DM + (j ^ (row & 7)) * 8, (char*)QVs + chunk * 16);
  }
  stageK(0);

  bf16x8 qb[2][2];  // [qf][dh]
  float rs[2] = {0.f, 0.f};

  // ---- pass 1: denominators ----
  for (int kt = 0; kt < LSEQ / 128; ++kt) {
    __syncthreads();
    if (kt == 0) {
#pragma unroll
      for (int qf = 0; qf < 2; ++qf)
#pragma unroll
        for (int dh = 0; dh < 2; ++dh)
          qb[qf][dh] = lds_frag_swz(QVs, qg * 32 + qf * 16 + lr, dh * 64 + lq * 16);
    }
#pragma unroll
    for (int kf = 0; kf < 4; ++kf) {
      int krow = kg * 64 + kf * 16 + lr;
      bf16x8 a0 = lds_frag_swz(Ks, krow, lq * 16);
      bf16x8 a1 = lds_frag_swz(Ks, krow, 64 + lq * 16);
      ushort4 m4 = *(const ushort4*)&Ms[kt * 128 + kg * 64 + kf * 16 + lq * 4];
#pragma unroll
      for (int qf = 0; qf < 2; ++qf) {
        f32x4 z = (f32x4){0.f, 0.f, 0.f, 0.f};
        z = __builtin_amdgcn_mfma_f32_16x16x32_bf16(a0, qb[qf][0], z, 0, 0, 0);
        z = __builtin_amdgcn_mfma_f32_16x16x32_bf16(a1, qb[qf][1], z, 0, 0, 0);
        rs[qf] += __builtin_amdgcn_exp2f(z[0] * k2) * bf16f(m4.x);
        rs[qf] += __builtin_amdgcn_exp2f(z[1] * k2) * bf16f(m4.y);
        rs[qf] += __builtin_amdgcn_exp2f(z[2] * k2) * bf16f(m4.z);
        rs[qf] += __builtin_amdgcn_exp2f(z[3] * k2) * bf16f(m4.w);
      }
    }
    __syncthreads();
    if (kt + 1 < LSEQ / 128) stageK((kt + 1) * 128);
  }
  // reduce rs over lq within wave, publish per (qg,kg)
#pragma unroll
  for (int qf = 0; qf < 2; ++qf) {
    rs[qf] += __shfl_xor(rs[qf], 16, 64);
    rs[qf] += __shfl_xor(rs[qf], 32, 64);
  }
  if (lq == 0) {
    Rs[qg][kg][lr] = rs[0];
    Rs[qg][kg][16 + lr] = rs[1];
  }
  __syncthreads();
  float sinv[2];
#pragma unroll
  for (int qf = 0; qf < 2; ++qf) {
    float tot = Rs[qg][0][qf * 16 + lr] + Rs[qg][1][qf * 16 + lr];
    sinv[qf] = 1.0f / fmaxf(tot, 1e-30f);
  }
  stageK(0);
  stageV(0);

  // ---- pass 2: recompute, NT-store attn, accumulate PV partials ----
  f32x4 acc[4][2];  // [df][qf]
#pragma unroll
  for (int df = 0; df < 4; ++df)
#pragma unroll
    for (int qf = 0; qf < 2; ++qf) acc[df][qf] = (f32x4){0.f, 0.f, 0.f, 0.f};
  const int sA = ((lane & 16) ? 32 : 0) + lr;  // bpermute source lanes
  const int sB = sA + 16;
  const bool selHi = (lane & 32) != 0;

  for (int kt = 0; kt < LSEQ / 128; ++kt) {
    __syncthreads();  // K,V staged
    unsigned pk[4][2][2];
#pragma unroll
    for (int kf = 0; kf < 4; ++kf) {
      int krow = kg * 64 + kf * 16 + lr;
      bf16x8 a0 = lds_frag_swz(Ks, krow, lq * 16);
      bf16x8 a1 = lds_frag_swz(Ks, krow, 64 + lq * 16);
      ushort4 m4 = *(const ushort4*)&Ms[kt * 128 + kg * 64 + kf * 16 + lq * 4];
#pragma unroll
      for (int qf = 0; qf < 2; ++qf) {
        f32x4 z = (f32x4){0.f, 0.f, 0.f, 0.f};
        z = __builtin_amdgcn_mfma_f32_16x16x32_bf16(a0, qb[qf][0], z, 0, 0, 0);
        z = __builtin_amdgcn_mfma_f32_16x16x32_bf16(a1, qb[qf][1], z, 0, 0, 0);
        float p0 = __builtin_amdgcn_exp2f(z[0] * k2) * bf16f(m4.x) * sinv[qf];
        float p1 = __builtin_amdgcn_exp2f(z[1] * k2) * bf16f(m4.y) * sinv[qf];
        float p2 = __builtin_amdgcn_exp2f(z[2] * k2) * bf16f(m4.z) * sinv[qf];
        float p3 = __builtin_amdgcn_exp2f(z[3] * k2) * bf16f(m4.w) * sinv[qf];
        f32x4 st = (f32x4){p0, p1, p2, p3};
        __builtin_nontemporal_store(
            st, (f32x4*)(attn_g + (size_t)(qg * 32 + qf * 16 + lr) * LSEQ + kt * 128 +
                         kg * 64 + kf * 16 + lq * 4));
        pk[kf][qf][0] = cvt_pk_bf16(p0, p1);
        pk[kf][qf][1] = cvt_pk_bf16(p2, p3);
      }
    }
    // PV: pb word j for lane lq covers keys kh*32+lq*8+2j{,+1}
#pragma unroll
    for (int kh = 0; kh < 2; ++kh) {
      bf16x8 pbv[2];
#pragma unroll
      for (int qf = 0; qf < 2; ++qf) {
        union { unsigned w[4]; bf16x8 v; } pb;
        unsigned lo0 = __shfl((int)pk[kh * 2][qf][0], sA, 64);
        unsigned hi0 = __shfl((int)pk[kh * 2 + 1][qf][0], sA, 64);
        unsigned lo1 = __shfl((int)pk[kh * 2][qf][1], sA, 64);
        unsigned hi1 = __shfl((int)pk[kh * 2 + 1][qf][1], sA, 64);
        unsigned lo2 = __shfl((int)pk[kh * 2][qf][0], sB, 64);
        unsigned hi2 = __shfl((int)pk[kh * 2 + 1][qf][0], sB, 64);
        unsigned lo3 = __shfl((int)pk[kh * 2][qf][1], sB, 64);
        unsigned hi3 = __shfl((int)pk[kh * 2 + 1][qf][1], sB, 64);
        pb.w[0] = selHi ? hi0 : lo0;
        pb.w[1] = selHi ? hi1 : lo1;
        pb.w[2] = selHi ? hi2 : lo2;
        pb.w[3] = selHi ? hi3 : lo3;
        pbv[qf] = pb.v;
      }
#pragma unroll
      for (int df = 0; df < 4; ++df) {
        bf16x8 va = lds_frag_swzV(QVs, df * 16 + lr, kg * 128 + kh * 64 + lq * 16);
#pragma unroll
        for (int qf = 0; qf < 2; ++qf)
          acc[df][qf] = __builtin_amdgcn_mfma_f32_16x16x32_bf16(va, pbv[qf], acc[df][qf], 0, 0, 0);
      }
    }
    __syncthreads();  // reads done
    if (kt + 1 < LSEQ / 128) { stageK((kt + 1) * 128); stageV((kt + 1) * 128); }
  }

  // ---- cross-wave k-reduction via LDS scratch (overlaid on Ks) ----
  __syncthreads();
  float* CR = (float*)Ks;  // [2 qg][32 q][64 d] f32, 16KB, swizzled
  if (kg == 1) {
#pragma unroll
    for (int df = 0; df < 4; ++df)
#pragma unroll
      for (int qf = 0; qf < 2; ++qf) {
        int q = qf * 16 + lr, dd = df * 16 + lq * 4;
        int byte = ((qg * 32 + q) * 64 + dd) * 4;
        byte ^= (q & 7) << 4;
        *(f32x4*)((char*)CR + byte) = acc[df][qf];
      }
  }
  __syncthreads();
  if (kg == 0) {
#pragma unroll
    for (int df = 0; df < 4; ++df)
#pragma unroll
      for (int qf = 0; qf < 2; ++qf) {
        int q = qf * 16 + lr, dd = df * 16 + lq * 4;
        int byte = ((qg * 32 + q) * 64 + dd) * 4;
        byte ^= (q & 7) << 4;
        f32x4 o = *(const f32x4*)((const char*)CR + byte);
        o += acc[df][qf];
        ushort4 st;
        st.x = bf16r(o[0]); st.y = bf16r(o[1]); st.z = bf16r(o[2]); st.w = bf16r(o[3]);
        *(ushort4*)&ctx[(size_t)(b * LSEQ + qt * 64 + qg * 32 + q) * DM + h * HD + dd] = st;
      }
  }
}

extern "C" void kernel_launch(void* const* d_in, const int* in_sizes, int n_in,
                              void* d_out, int out_size, void* d_ws, size_t ws_size,
                              hipStream_t stream) {
  const float* query = (const float*)d_in[0];
  const float* key_ = (const float*)d_in[1];
  const float* value = (const float*)d_in[2];
  const int* mask = (const int*)d_in[3];
  const float* Wq = (const float*)d_in[4];
  const float* bq = (const float*)d_in[5];
  const float* Wk = (const float*)d_in[6];
  const float* bk = (const float*)d_in[7];
  const float* Wv = (const float*)d_in[8];
  const float* bv = (const float*)d_in[9];
  const float* Wo = (const float*)d_in[10];
  const float* bo = (const float*)d_in[11];
  const float* scale = (const float*)d_in[12];

  char* ws = (char*)d_ws;
  const size_t XB = 8388608;   // 4Mi bf16
  const size_t WB = 2097152;   // 1Mi bf16
  unsigned short* qb = (unsigned short*)(ws);
  unsigned short* kb = (unsigned short*)(ws + XB);
  unsigned short* vb = (unsigned short*)(ws + 2 * XB);
  unsigned short* wqb = (unsigned short*)(ws + 3 * XB);
  unsigned short* wkb = (unsigned short*)(ws + 3 * XB + WB);
  unsigned short* wvb = (unsigned short*)(ws + 3 * XB + 2 * WB);
  unsigned short* wob = (unsigned short*)(ws + 3 * XB + 3 * WB);
  unsigned short* Qnb = (unsigned short*)(ws + 3 * XB + 4 * WB);
  unsigned short* Knb = (unsigned short*)(ws + 4 * XB + 4 * WB);
  unsigned short* Vtb = (unsigned short*)(ws + 5 * XB + 4 * WB);
  unsigned short* ctxb = (unsigned short*)(ws + 6 * XB + 4 * WB);

  cvt3<<<dim3(2048, 3), 256, 0, stream>>>(query, key_, value, qb, kb, vb, 524288);
  cvt4<<<dim3(512, 4), 256, 0, stream>>>(Wq, Wk, Wv, Wo, wqb, wkb, wvb, wob, 131072);

  gemm_qkv<<<dim3(32, 8, 3), 256, 0, stream>>>(qb, kb, vb, wqb, wkb, wvb, bq, bk, bv,
                                               Qnb, Knb, Vtb);

  float* attn_out = (float*)d_out + 4194304;
  attn_kernel<<<1024, 256, 0, stream>>>(Qnb, Knb, Vtb, mask, scale, attn_out, ctxb);

  gemm_o<<<dim3(32, 8), 256, 0, stream>>>(ctxb, wob, bo, (float*)d_out);
}